// Round 9
// baseline (237.116 us; speedup 1.0000x reference)
//
#include <hip/hip_runtime.h>
#include <math.h>

#define T_LEN 32000
#define B_N 8
#define O_N 128
#define NTAPS 10
#define NTHREADS 256
#define UT 8                          // consecutive t per lane
#define TILE_T (NTHREADS * UT)        // 2048
#define PAD 2944                      // >= ceil(9*Dmax)+margin, Dmax = 320
#define NSTAGE (TILE_T + PAD + 1)     // 4993 pairs
#define NSTAGE_AL ((NSTAGE + 3) & ~3) // 4996 pairs
#define SK(p) ((p) + ((p) >> 4))      // skew: +1 slot per 16 pairs (bank spread)
#define NSLOTS (NSTAGE_AL + (NSTAGE_AL >> 4))  // 5308 float2 = 42.5 KB LDS
#define OCHUNK 8
#define TC 1024                       // tile-center offset (const-frac quantization)

// ---------------- kernel 1: per-channel tap parameters -> d_ws ----------------
// f = fl32(50 * 40^sigmoid(f_raw)), D = fl32(16000/f), kD = fl32(k*D), a^k.
// f64 for sigmoid/pow accuracy, one final rounding to f32.
__global__ __launch_bounds__(128) void comb_params_kernel(
    const float* __restrict__ f, const float* __restrict__ a,
    float* __restrict__ tp) {
  int o = threadIdx.x;  // 128 threads, 1 block
  double fr = (double)f[o];
  double sig = 1.0 / (1.0 + exp(-fr));
  float ff = (float)(50.0 * pow(40.0, sig));
  float D = 16000.0f / ff;
  float av = a[o];
  for (int k = 0; k < NTAPS; ++k) {
    tp[o * 20 + k] = (float)k * D;
    tp[o * 20 + 10 + k] = (float)pow((double)av, (double)k);
  }
}

#define LOAD_PARAMS                                                        \
  const float4* p4 = (const float4*)(tp + (oc + oi) * 20);                 \
  float4 q0 = p4[0], q1 = p4[1], q2 = p4[2], q3 = p4[3], q4 = p4[4];       \
  float kD[NTAPS] = {q0.x, q0.y, q0.z, q0.w, q1.x,                         \
                     q1.y, q1.z, q1.w, q2.x, q2.y};                        \
  float ak[NTAPS] = {q2.z, q2.w, q3.x, q3.y, q3.z,                         \
                     q3.w, q4.x, q4.y, q4.z, q4.w};

// ---------------- fast body (bx >= 2: all taps valid, const-frac) ------------
// Const-frac (R7/R8, absmax-neutral) + 8 consecutive t per lane: one (o,k)
// tap for 8 outputs needs x[i..i+9] -> 5 skewed ds_read_b64 = 4.5 B/tap.
// Skew makes lane pair-stride 8 hit all 16 even banks uniformly (4/bank =
// structural wave64-b64 minimum). Stores: two coalesced float4 per oi.
__device__ __forceinline__ void comb_body_fast(const float* __restrict__ tp,
                                               float* __restrict__ outp,
                                               const float2* sx2, int oc,
                                               int t0, int tid, bool do_store) {
  float tcf = (float)(t0 + TC);
  int cbase = PAD - t0 - TC + UT * tid;
  // k=0 (identity tap): x[t..t+7], reused across all oi
  int b0 = PAD + UT * tid;
  float2 A0 = sx2[SK(b0)], B0 = sx2[SK(b0 + 2)];
  float2 C0 = sx2[SK(b0 + 4)], D0 = sx2[SK(b0 + 6)];
#pragma unroll 1
  for (int oi = 0; oi < OCHUNK; ++oi) {
    LOAD_PARAMS
    float acc[UT] = {A0.x, A0.y, B0.x, B0.y, C0.x, C0.y, D0.x, D0.y};
#pragma unroll
    for (int k = 1; k < NTAPS; ++k) {
      float pc = tcf - kD[k];                  // reference pos at t_c (>0 here)
      float fc = __builtin_amdgcn_fractf(pc);  // frac_ref(t_c), exact
      int sb = (int)(pc - fc) + cbase;         // pc-fc == floor(pc) exactly
      float w1 = ak[k] * fc;
      float w0 = ak[k] - w1;
      float2 A = sx2[SK(sb)];                  // x[i]  , x[i+1]
      float2 B = sx2[SK(sb + 2)];              // x[i+2], x[i+3]
      float2 C = sx2[SK(sb + 4)];              // x[i+4], x[i+5]
      float2 D = sx2[SK(sb + 6)];              // x[i+6], x[i+7]
      float2 E = sx2[SK(sb + 8)];              // x[i+8], (x[i+9] unused)
      acc[0] = fmaf(w0, A.x, fmaf(w1, A.y, acc[0]));
      acc[1] = fmaf(w0, A.y, fmaf(w1, B.x, acc[1]));
      acc[2] = fmaf(w0, B.x, fmaf(w1, B.y, acc[2]));
      acc[3] = fmaf(w0, B.y, fmaf(w1, C.x, acc[3]));
      acc[4] = fmaf(w0, C.x, fmaf(w1, C.y, acc[4]));
      acc[5] = fmaf(w0, C.y, fmaf(w1, D.x, acc[5]));
      acc[6] = fmaf(w0, D.x, fmaf(w1, D.y, acc[6]));
      acc[7] = fmaf(w0, D.y, fmaf(w1, E.x, acc[7]));
    }
    if (do_store) {
      float4* o4 = (float4*)(outp + (size_t)oi * T_LEN);  // 16B-aligned
      o4[0] = make_float4(acc[0], acc[1], acc[2], acc[3]);
      o4[1] = make_float4(acc[4], acc[5], acc[6], acc[7]);
    }
  }
}

// ---------------- exact body (edge tiles bx 0..1: per-t arithmetic + mask) ---
// Quantized-frac i0 flips at the i0==-1 mask boundary can produce O(1) errors,
// so edge tiles keep the bit-faithful per-element chain (12.5% of blocks).
__device__ __forceinline__ void comb_body_edge(const float* __restrict__ tp,
                                               float* __restrict__ outp,
                                               const float2* sx2, int oc,
                                               int t0, int tid, int base_g) {
  float tf[UT];
#pragma unroll
  for (int u = 0; u < UT; ++u) tf[u] = (float)(t0 + UT * tid + u);
#pragma unroll 1
  for (int oi = 0; oi < OCHUNK; ++oi) {
    LOAD_PARAMS
    float acc[UT];
#pragma unroll
    for (int u = 0; u < UT; ++u) acc[u] = 0.0f;
#pragma unroll
    for (int k = 0; k < NTAPS; ++k) {
#pragma unroll
      for (int u = 0; u < UT; ++u) {
        float pos = tf[u] - kD[k];                  // fl(t - kD), exact chain
        float frac = __builtin_amdgcn_fractf(pos);
        int idx = (int)pos - base_g;                // trunc==floor for pos>=0
        float2 xv = sx2[SK(idx)];                   // neg-pos taps masked below
        float tap = fmaf(frac, xv.y - xv.x, xv.x);
        tap = (pos >= 0.0f) ? tap : 0.0f;           // valid = (floor(pos)>=0)
        acc[u] = fmaf(ak[k], tap, acc[u]);
      }
    }
    float4* o4 = (float4*)(outp + (size_t)oi * T_LEN);
    o4[0] = make_float4(acc[0], acc[1], acc[2], acc[3]);
    o4[1] = make_float4(acc[4], acc[5], acc[6], acc[7]);
  }
}

__global__ __launch_bounds__(256) void comb_main_kernel(
    const float* __restrict__ x, const float* __restrict__ tp,
    float* __restrict__ out) {
  __shared__ float2 sx2[NSLOTS];
  int bx = blockIdx.x;
  int t0 = bx * TILE_T;
  int b = blockIdx.y;
  int oc = blockIdx.z * OCHUNK;
  const float* __restrict__ xrow = x + b * T_LEN;
  int base_g = t0 - PAD;
  int tid = threadIdx.x;

  if (bx >= 2 && bx <= 14) {
    // interior: window fully inside [0, 31999] -> aligned float4 staging
    const float4* g4 = (const float4*)(xrow + base_g);
#pragma unroll 1
    for (int jq = tid; jq < NSTAGE_AL / 4; jq += 256) {
      float4 v = g4[jq];
      float nx = xrow[base_g + 4 * jq + 4];
      int p = 4 * jq;
      sx2[SK(p)]     = make_float2(v.x, v.y);
      sx2[SK(p + 1)] = make_float2(v.y, v.z);
      sx2[SK(p + 2)] = make_float2(v.z, v.w);
      sx2[SK(p + 3)] = make_float2(v.w, nx);
    }
  } else if (bx == 15) {
    // tail: float4 while g+4 <= 31999 (quads 0..1054), then scalar clamp
    const float4* g4 = (const float4*)(xrow + base_g);
#pragma unroll 1
    for (int jq = tid; jq < 1055; jq += 256) {
      float4 v = g4[jq];
      float nx = xrow[base_g + 4 * jq + 4];
      int p = 4 * jq;
      sx2[SK(p)]     = make_float2(v.x, v.y);
      sx2[SK(p + 1)] = make_float2(v.y, v.z);
      sx2[SK(p + 2)] = make_float2(v.z, v.w);
      sx2[SK(p + 3)] = make_float2(v.w, nx);
    }
#pragma unroll 1
    for (int p = 4220 + tid; p < NSTAGE_AL; p += 256) {
      int g = base_g + p;
      float v0 = xrow[g < T_LEN - 1 ? g : T_LEN - 1];
      float v1 = xrow[g + 1 < T_LEN - 1 ? g + 1 : T_LEN - 1];
      sx2[SK(p)] = make_float2(v0, v1);  // clip(i0+1) semantics, weight 0
    }
  } else {
    // bx 0,1: g<0 -> 0.0 (invalid-tap reads are finite / masked)
#pragma unroll 1
    for (int p = tid; p < NSTAGE_AL; p += 256) {
      int g = base_g + p;
      float v0 = 0.0f, v1 = 0.0f;
      if (g >= 0) v0 = xrow[g < T_LEN - 1 ? g : T_LEN - 1];
      if (g + 1 >= 0) v1 = xrow[g + 1 < T_LEN - 1 ? g + 1 : T_LEN - 1];
      sx2[SK(p)] = make_float2(v0, v1);
    }
  }
  __syncthreads();

  float* outp = out + ((size_t)b * O_N + oc) * T_LEN + t0 + UT * tid;

  if (bx >= 2) {
    // bx==15: 32000-30720 = 1280 = 8*160 -> lanes tid<160 store, rest discard
    comb_body_fast(tp, outp, sx2, oc, t0, tid, bx < 15 || tid < 160);
  } else {
    comb_body_edge(tp, outp, sx2, oc, t0, tid, base_g);
  }
}

// ---------------- launch ----------------
extern "C" void kernel_launch(void* const* d_in, const int* in_sizes, int n_in,
                              void* d_out, int out_size, void* d_ws,
                              size_t ws_size, hipStream_t stream) {
  const float* x = (const float*)d_in[0];  // (8,1,32000) f32
  const float* f = (const float*)d_in[1];  // (128,1) f32
  const float* a = (const float*)d_in[2];  // (128,1) f32
  float* out = (float*)d_out;              // (8,128,32000) f32
  float* tp = (float*)d_ws;                // 128*20 floats = 10 KB scratch

  comb_params_kernel<<<1, 128, 0, stream>>>(f, a, tp);

  dim3 grid(16, B_N, O_N / OCHUNK);  // (16, 8, 16) = 2048 blocks
  comb_main_kernel<<<grid, 256, 0, stream>>>(x, tp, out);
}